// Round 12
// baseline (190.071 us; speedup 1.0000x reference)
//
#include <hip/hip_runtime.h>

#define NSEQ 1024
#define CA   768
#define CZ   128
#define NH   16
#define CHD  48
#define HC   768
#define INV_SQRT_CH 0.14433756729740643f

typedef float v4f __attribute__((ext_vector_type(4)));
typedef short v8s __attribute__((ext_vector_type(8)));

__device__ __forceinline__ short f2bf(float f) {
  union { float f; unsigned u; } v; v.f = f;
  unsigned r = v.u + 0x7fffu + ((v.u >> 16) & 1u);
  return (short)(r >> 16);
}
__device__ __forceinline__ float bf2f(short s) {
  union { unsigned u; float f; } v;
  v.u = ((unsigned)(unsigned short)s) << 16;
  return v.f;
}
__device__ __forceinline__ unsigned cvtpk(float lo, float hi) {
  unsigned r;
  asm("v_cvt_pk_bf16_f32 %0, %1, %2" : "=v"(r) : "v"(lo), "v"(hi));
  return r;
}

// ---------------- K23: mega {0..191 = self-LN QKVG GEMM} + {192..4287 = self-prep z-bias} ----------------
__global__ __launch_bounds__(256, 2) void k23_mega(
    const float* __restrict__ a, const float* __restrict__ lnaw,
    const float* __restrict__ lnab,
    const float* __restrict__ Wq, const float* __restrict__ Wk,
    const float* __restrict__ Wv, const float* __restrict__ Wg,
    const float* __restrict__ bq, const float* __restrict__ z,
    const float* __restrict__ lnzw, const float* __restrict__ lnzb,
    const float* __restrict__ Wb,
    short* __restrict__ qb, short* __restrict__ kb, short* __restrict__ vT,
    float* __restrict__ gbuf, short* __restrict__ bpair)
{
  __shared__ __align__(16) char smem[21504];
  const int tid = threadIdx.x;
  const int w = tid >> 6, l = tid & 63;
  const int r16 = l & 15, cg = l >> 4;

  if (blockIdx.x < 192) {
    // ---------- QKVG bf16 MFMA GEMM, self-LN A, self-convert B ----------
    short* As = (short*)smem;            // [128][40]
    short* Bs = (short*)(smem + 10240);  // [128][40]
    float* stats = (float*)(smem + 20480);  // [128][2] m, rs
    const int bm = blockIdx.x & 7;
    const int bnb = blockIdx.x >> 3;     // 0..23
    const int m0 = bm * 128, n0 = bnb * 128;
    const int matsel = n0 / HC;
    const float* __restrict__ Wsrc =
        (matsel == 0) ? Wq : (matsel == 1) ? Wk : (matsel == 2) ? Wv : Wg;
    const float wscale = (matsel == 0) ? INV_SQRT_CH : 1.f;
    const int wr = w >> 1, wc = w & 1;
    const int strow = w * 16 + (l >> 2);
    const int scol = (l & 3) * 8;

    // ---- LN stats: row = tid>>1, half = tid&1, 384 floats each ----
    {
      const int row = tid >> 1, half = tid & 1;
      const float* ar = a + (size_t)(m0 + row) * CA + half * 384;
      float s = 0.f, s2 = 0.f;
      for (int i = 0; i < 96; ++i) {
        v4f x = *(const v4f*)(ar + i * 4);
        s += (x[0] + x[1]) + (x[2] + x[3]);
        s2 += (x[0] * x[0] + x[1] * x[1]) + (x[2] * x[2] + x[3] * x[3]);
      }
      s += __shfl_xor(s, 1);
      s2 += __shfl_xor(s2, 1);
      if (half == 0) {
        const float m = s * (1.f / CA);
        const float var = s2 * (1.f / CA) - m * m;
        stats[row * 2] = m;
        stats[row * 2 + 1] = rsqrtf(var + 1e-5f);
      }
    }
    __syncthreads();

    const float mA0 = stats[strow * 2],        rA0 = stats[strow * 2 + 1];
    const float mA1 = stats[(64 + strow) * 2], rA1 = stats[(64 + strow) * 2 + 1];
    const int ncb = (n0 % HC) + strow;

    v4f acc[4][4];
    #pragma unroll
    for (int i = 0; i < 4; ++i)
      #pragma unroll
      for (int j = 0; j < 4; ++j)
        acc[i][j] = (v4f){0.f, 0.f, 0.f, 0.f};

    for (int k0 = 0; k0 < CA; k0 += 32) {
      // A: fp32 + LN -> bf16
      v4f x0 = *(const v4f*)(a + (size_t)(m0 + strow) * CA + k0 + scol);
      v4f x1 = *(const v4f*)(a + (size_t)(m0 + strow) * CA + k0 + scol + 4);
      v4f y0 = *(const v4f*)(a + (size_t)(m0 + 64 + strow) * CA + k0 + scol);
      v4f y1 = *(const v4f*)(a + (size_t)(m0 + 64 + strow) * CA + k0 + scol + 4);
      v4f lw0 = *(const v4f*)(lnaw + k0 + scol);
      v4f lw1 = *(const v4f*)(lnaw + k0 + scol + 4);
      v4f lb0 = *(const v4f*)(lnab + k0 + scol);
      v4f lb1 = *(const v4f*)(lnab + k0 + scol + 4);
      // B: fp32 column reads -> bf16
      float b0f[8], b1f[8];
      #pragma unroll
      for (int j = 0; j < 8; ++j) {
        b0f[j] = Wsrc[(size_t)(k0 + scol + j) * HC + ncb] * wscale;
        b1f[j] = Wsrc[(size_t)(k0 + scol + j) * HC + ncb + 64] * wscale;
      }
      uint4 pa0, pa1, pb0, pb1;
      pa0.x = cvtpk((x0[0]-mA0)*rA0*lw0[0]+lb0[0], (x0[1]-mA0)*rA0*lw0[1]+lb0[1]);
      pa0.y = cvtpk((x0[2]-mA0)*rA0*lw0[2]+lb0[2], (x0[3]-mA0)*rA0*lw0[3]+lb0[3]);
      pa0.z = cvtpk((x1[0]-mA0)*rA0*lw1[0]+lb1[0], (x1[1]-mA0)*rA0*lw1[1]+lb1[1]);
      pa0.w = cvtpk((x1[2]-mA0)*rA0*lw1[2]+lb1[2], (x1[3]-mA0)*rA0*lw1[3]+lb1[3]);
      pa1.x = cvtpk((y0[0]-mA1)*rA1*lw0[0]+lb0[0], (y0[1]-mA1)*rA1*lw0[1]+lb0[1]);
      pa1.y = cvtpk((y0[2]-mA1)*rA1*lw0[2]+lb0[2], (y0[3]-mA1)*rA1*lw0[3]+lb0[3]);
      pa1.z = cvtpk((y1[0]-mA1)*rA1*lw1[0]+lb1[0], (y1[1]-mA1)*rA1*lw1[1]+lb1[1]);
      pa1.w = cvtpk((y1[2]-mA1)*rA1*lw1[2]+lb1[2], (y1[3]-mA1)*rA1*lw1[3]+lb1[3]);
      pb0.x = cvtpk(b0f[0], b0f[1]); pb0.y = cvtpk(b0f[2], b0f[3]);
      pb0.z = cvtpk(b0f[4], b0f[5]); pb0.w = cvtpk(b0f[6], b0f[7]);
      pb1.x = cvtpk(b1f[0], b1f[1]); pb1.y = cvtpk(b1f[2], b1f[3]);
      pb1.z = cvtpk(b1f[4], b1f[5]); pb1.w = cvtpk(b1f[6], b1f[7]);
      __syncthreads();
      *(uint4*)(As + (size_t)strow * 40 + scol) = pa0;
      *(uint4*)(As + (size_t)(64 + strow) * 40 + scol) = pa1;
      *(uint4*)(Bs + (size_t)strow * 40 + scol) = pb0;
      *(uint4*)(Bs + (size_t)(64 + strow) * 40 + scol) = pb1;
      __syncthreads();
      v8s af[4], bf[4];
      #pragma unroll
      for (int m = 0; m < 4; ++m)
        af[m] = *(const v8s*)(As + (wr * 64 + m * 16 + r16) * 40 + cg * 8);
      #pragma unroll
      for (int n = 0; n < 4; ++n)
        bf[n] = *(const v8s*)(Bs + (wc * 64 + n * 16 + r16) * 40 + cg * 8);
      #pragma unroll
      for (int m = 0; m < 4; ++m)
        #pragma unroll
        for (int n = 0; n < 4; ++n)
          acc[m][n] = __builtin_amdgcn_mfma_f32_16x16x32_bf16(af[m], bf[n], acc[m][n], 0, 0, 0);
    }

    #pragma unroll
    for (int n = 0; n < 4; ++n) {
      const int nc = (n0 % HC) + wc * 64 + n * 16 + r16;
      const int rbase = m0 + wr * 64 + cg * 4;
      if (matsel == 0) {
        const float bqs = bq[nc] * INV_SQRT_CH;
        #pragma unroll
        for (int m = 0; m < 4; ++m)
          #pragma unroll
          for (int j = 0; j < 4; ++j)
            qb[(size_t)(rbase + m * 16 + j) * HC + nc] = f2bf(acc[m][n][j] + bqs);
      } else if (matsel == 1) {
        #pragma unroll
        for (int m = 0; m < 4; ++m)
          #pragma unroll
          for (int j = 0; j < 4; ++j)
            kb[(size_t)(rbase + m * 16 + j) * HC + nc] = f2bf(acc[m][n][j]);
      } else if (matsel == 2) {
        #pragma unroll
        for (int m = 0; m < 4; ++m) {
          uint2 pk;
          pk.x = cvtpk(acc[m][n][0], acc[m][n][1]);
          pk.y = cvtpk(acc[m][n][2], acc[m][n][3]);
          *(uint2*)(vT + (size_t)nc * NSEQ + rbase + m * 16) = pk;
        }
      } else {
        #pragma unroll
        for (int m = 0; m < 4; ++m)
          #pragma unroll
          for (int j = 0; j < 4; ++j)
            gbuf[(size_t)(rbase + m * 16 + j) * HC + nc] =
                1.f / (1.f + __expf(-acc[m][n][j]));
      }
    }
  } else {
    // ---------- z-bias, self-prep, barrier-free, software-pipelined ----------
    const int zbid = blockIdx.x - 192;   // 0..4095
    short* bl = (short*)smem + w * (16 * 68);
    const int q = zbid >> 2;
    const int kw = ((zbid & 3) << 8) + w * 64;

    // self-prep bfrag + S1 + bW (replaces wWp/S1bW precompute)
    v8s bfrag[4];
    float s1 = 0.f, bwp = 0.f;
    #pragma unroll
    for (int ss = 0; ss < 4; ++ss) {
      unsigned up[4];
      #pragma unroll
      for (int jj = 0; jj < 4; ++jj) {
        const int d0 = ss * 32 + cg * 8 + jj * 2;
        const float wb0 = Wb[d0 * NH + r16];
        const float wb1 = Wb[(d0 + 1) * NH + r16];
        const short c0 = f2bf(lnzw[d0] * wb0);
        const short c1 = f2bf(lnzw[d0 + 1] * wb1);
        s1 += bf2f(c0) + bf2f(c1);
        bwp += lnzb[d0] * wb0 + lnzb[d0 + 1] * wb1;
        up[jj] = (unsigned)(unsigned short)c0 | ((unsigned)(unsigned short)c1 << 16);
      }
      union { v8s s8; unsigned u[4]; } fu;
      fu.u[0] = up[0]; fu.u[1] = up[1]; fu.u[2] = up[2]; fu.u[3] = up[3];
      bfrag[ss] = fu.s8;
    }
    s1  += __shfl_xor(s1, 16);  s1  += __shfl_xor(s1, 32);
    bwp += __shfl_xor(bwp, 16); bwp += __shfl_xor(bwp, 32);
    const float S1 = s1;
    const float bW = bwp;

    const float* __restrict__ zbase = z + ((size_t)q * NSEQ + kw + r16) * CZ;

    v4f zb[8];
    #pragma unroll
    for (int ss = 0; ss < 4; ++ss) {
      zb[2 * ss]     = *(const v4f*)(zbase + ss * 32 + cg * 8);
      zb[2 * ss + 1] = *(const v4f*)(zbase + ss * 32 + cg * 8 + 4);
    }

    for (int kt = 0; kt < 4; ++kt) {
      v4f zn[8];
      if (kt < 3) {
        const float* __restrict__ zr2 = zbase + (size_t)(kt + 1) * 16 * CZ;
        #pragma unroll
        for (int ss = 0; ss < 4; ++ss) {
          zn[2 * ss]     = *(const v4f*)(zr2 + ss * 32 + cg * 8);
          zn[2 * ss + 1] = *(const v4f*)(zr2 + ss * 32 + cg * 8 + 4);
        }
      }

      float sum = 0.f, sum2 = 0.f;
      v8s afrag[4];
      #pragma unroll
      for (int ss = 0; ss < 4; ++ss) {
        v4f z0 = zb[2 * ss], z1 = zb[2 * ss + 1];
        #pragma unroll
        for (int j = 0; j < 4; ++j) {
          sum += z0[j] + z1[j];
          sum2 += z0[j] * z0[j] + z1[j] * z1[j];
        }
        union { v8s s8; unsigned u[4]; } fu;
        fu.u[0] = cvtpk(z0[0], z0[1]);
        fu.u[1] = cvtpk(z0[2], z0[3]);
        fu.u[2] = cvtpk(z1[0], z1[1]);
        fu.u[3] = cvtpk(z1[2], z1[3]);
        afrag[ss] = fu.s8;
      }
      sum  += __shfl_xor(sum, 16);  sum  += __shfl_xor(sum, 32);
      sum2 += __shfl_xor(sum2, 16); sum2 += __shfl_xor(sum2, 32);
      const float mean = sum * (1.f / CZ);
      const float var = sum2 * (1.f / CZ) - mean * mean;
      const float rs = rsqrtf(var + 1e-5f);

      v4f acc = {0.f, 0.f, 0.f, 0.f};
      #pragma unroll
      for (int ss = 0; ss < 4; ++ss)
        acc = __builtin_amdgcn_mfma_f32_16x16x32_bf16(afrag[ss], bfrag[ss], acc, 0, 0, 0);

      float bv[4];
      #pragma unroll
      for (int j = 0; j < 4; ++j) {
        int src = cg * 4 + j;
        float mj = __shfl(mean, src);
        float rj = __shfl(rs, src);
        bv[j] = rj * (acc[j] - mj * S1) + bW;
      }
      *(unsigned*)&bl[r16 * 68 + kt * 16 + cg * 4]     = cvtpk(bv[0], bv[1]);
      *(unsigned*)&bl[r16 * 68 + kt * 16 + cg * 4 + 2] = cvtpk(bv[2], bv[3]);

      if (kt < 3) {
        #pragma unroll
        for (int i = 0; i < 8; ++i) zb[i] = zn[i];
      }
    }

    asm volatile("s_waitcnt lgkmcnt(0)" ::: "memory");
    __builtin_amdgcn_sched_barrier(0);

    const int h = l >> 2, ck = (l & 3) * 16;
    v8s o0 = *(const v8s*)(bl + h * 68 + ck);
    v8s o1 = *(const v8s*)(bl + h * 68 + ck + 8);
    short* dst = bpair + (size_t)h * NSEQ * NSEQ + (size_t)q * NSEQ + kw + ck;
    *(v8s*)(dst)     = o0;
    *(v8s*)(dst + 8) = o1;
  }
}

// ---------------- K45: flash attention + in-block combine + gate ----------------
#define PL_STRIDE 136
#define PO_STRIDE 52
__global__ __launch_bounds__(512) void k45_attn(
    const short* __restrict__ qb, const short* __restrict__ kb,
    const short* __restrict__ vT, const short* __restrict__ bpair,
    const float* __restrict__ mask, const float* __restrict__ gbuf,
    short* __restrict__ gob)
{
  const int h = blockIdx.x & 15;
  const int qt = blockIdx.x >> 4;
  const int tid = threadIdx.x;
  const int w = tid >> 6, l = tid & 63;
  const int r16 = l & 15, cg = l >> 4;
  const int q0 = qt * 16;
  const int k0 = w * 128;

  __shared__ __align__(16) short plds[8][16 * PL_STRIDE];
  __shared__ __align__(16) float po_lds[8][16][PO_STRIDE];
  __shared__ __align__(16) float ml_lds[8][16][2];
  short* pl = &plds[w][0];

  const v8s vzero = {0, 0, 0, 0, 0, 0, 0, 0};
  v8s qf0, qf1;
  {
    const short* qp = qb + (size_t)(q0 + r16) * HC + h * CHD;
    qf0 = *(const v8s*)(qp + cg * 8);
    qf1 = (cg < 2) ? *(const v8s*)(qp + 32 + cg * 8) : vzero;
  }

  const size_t bpb = (size_t)h * NSEQ * NSEQ;
  {
    const int srow = l >> 2;
    const int scol = (l & 3) * 32;
    const short* bsrc = bpair + bpb + (size_t)(q0 + srow) * NSEQ + k0 + scol;
    short* bdst = pl + srow * PL_STRIDE + scol;
    v8s t0 = *(const v8s*)(bsrc);
    v8s t1 = *(const v8s*)(bsrc + 8);
    v8s t2 = *(const v8s*)(bsrc + 16);
    v8s t3 = *(const v8s*)(bsrc + 24);
    *(v8s*)(bdst)      = t0;
    *(v8s*)(bdst + 8)  = t1;
    *(v8s*)(bdst + 16) = t2;
    *(v8s*)(bdst + 24) = t3;
  }

  v4f cs[8];
  #pragma unroll
  for (int kt = 0; kt < 8; ++kt) {
    const short* kp = kb + (size_t)(k0 + kt * 16 + r16) * HC + h * CHD;
    v8s b0 = *(const v8s*)(kp + cg * 8);
    v8s b1 = (cg < 2) ? *(const v8s*)(kp + 32 + cg * 8) : vzero;
    v4f tacc = {0.f, 0.f, 0.f, 0.f};
    tacc = __builtin_amdgcn_mfma_f32_16x16x32_bf16(qf0, b0, tacc, 0, 0, 0);
    tacc = __builtin_amdgcn_mfma_f32_16x16x32_bf16(qf1, b1, tacc, 0, 0, 0);
    cs[kt] = tacc;
  }

  #pragma unroll
  for (int kt = 0; kt < 8; ++kt) {
    const int kc = k0 + kt * 16 + r16;
    const float mb = (mask[kc] - 1.f) * 1e9f;
    #pragma unroll
    for (int j = 0; j < 4; ++j)
      cs[kt][j] += bf2f(pl[(cg * 4 + j) * PL_STRIDE + kt * 16 + r16]) + mb;
  }

  float mx4[4], ls4[4];
  #pragma unroll
  for (int j = 0; j < 4; ++j) {
    float mx = fmaxf(fmaxf(fmaxf(cs[0][j], cs[1][j]), fmaxf(cs[2][j], cs[3][j])),
                     fmaxf(fmaxf(cs[4][j], cs[5][j]), fmaxf(cs[6][j], cs[7][j])));
    mx = fmaxf(mx, __shfl_xor(mx, 1));
    mx = fmaxf(mx, __shfl_xor(mx, 2));
    mx = fmaxf(mx, __shfl_xor(mx, 4));
    mx = fmaxf(mx, __shfl_xor(mx, 8));
    mx4[j] = mx;
    float p[8];
    #pragma unroll
    for (int kt = 0; kt < 8; ++kt) p[kt] = __expf(cs[kt][j] - mx);
    float rsum = ((p[0] + p[1]) + (p[2] + p[3])) + ((p[4] + p[5]) + (p[6] + p[7]));
    rsum += __shfl_xor(rsum, 1);
    rsum += __shfl_xor(rsum, 2);
    rsum += __shfl_xor(rsum, 4);
    rsum += __shfl_xor(rsum, 8);
    ls4[j] = rsum;
    const int rowb = (cg * 4 + j) * PL_STRIDE;
    #pragma unroll
    for (int t2 = 0; t2 < 4; ++t2) {
      unsigned u = cvtpk(p[2 * t2], p[2 * t2 + 1]);
      pl[rowb + (2 * t2) * 16 + r16] = (short)u;
      pl[rowb + (2 * t2 + 1) * 16 + r16] = (short)(u >> 16);
    }
  }
  asm volatile("s_waitcnt lgkmcnt(0)" ::: "memory");
  __builtin_amdgcn_sched_barrier(0);

  v4f of0 = {0, 0, 0, 0}, of1 = {0, 0, 0, 0}, of2 = {0, 0, 0, 0};
  #pragma unroll
  for (int ks4 = 0; ks4 < 4; ++ks4) {
    v8s pa = *(const v8s*)(pl + r16 * PL_STRIDE + ks4 * 32 + cg * 8);
    const short* vp = vT + (size_t)(h * CHD + r16) * NSEQ + k0 + ks4 * 32 + cg * 8;
    v8s bv0 = *(const v8s*)vp;
    v8s bv1 = *(const v8s*)(vp + 16 * NSEQ);
    v8s bv2 = *(const v8s*)(vp + 32 * NSEQ);
    of0 = __builtin_amdgcn_mfma_f32_16x16x32_bf16(pa, bv0, of0, 0, 0, 0);
    of1 = __builtin_amdgcn_mfma_f32_16x16x32_bf16(pa, bv1, of1, 0, 0, 0);
    of2 = __builtin_amdgcn_mfma_f32_16x16x32_bf16(pa, bv2, of2, 0, 0, 0);
  }

  #pragma unroll
  for (int j = 0; j < 4; ++j) {
    const int row = cg * 4 + j;
    po_lds[w][row][r16]      = of0[j];
    po_lds[w][row][16 + r16] = of1[j];
    po_lds[w][row][32 + r16] = of2[j];
    if (r16 == 0) {
      ml_lds[w][row][0] = mx4[j];
      ml_lds[w][row][1] = ls4[j];
    }
  }
  __syncthreads();

  {
    const int g = tid >> 5;
    const int lane = tid & 31;
    float mi[8], li[8];
    #pragma unroll
    for (int i = 0; i < 8; ++i) {
      mi[i] = ml_lds[i][g][0];
      li[i] = ml_lds[i][g][1];
    }
    float mstar = -1e30f;
    #pragma unroll
    for (int i = 0; i < 8; ++i) mstar = fmaxf(mstar, mi[i]);
    float wgt[8], L = 0.f;
    #pragma unroll
    for (int i = 0; i < 8; ++i) { wgt[i] = __expf(mi[i] - mstar); L += li[i] * wgt[i]; }
    const float inv = 1.f / L;
    const int q = q0 + g;
    {
      float o = 0.f;
      #pragma unroll
      for (int i = 0; i < 8; ++i) o += po_lds[i][g][lane] * wgt[i];
      const float gv = gbuf[(size_t)q * HC + h * CHD + lane];
      gob[(size_t)q * HC + h * CHD + lane] = f2bf(o * inv * gv);
    }
    if (lane < 16) {
      const int d = 32 + lane;
      float o = 0.f;
      #pragma unroll
      for (int i = 0; i < 8; ++i) o += po_lds[i][g][d] * wgt[i];
      const float gv = gbuf[(size_t)q * HC + h * CHD + d];
      gob[(size_t)q * HC + h * CHD + d] = f2bf(o * inv * gv);
    }
  }
}

// ---------------- K5: out = gob @ Wo (bf16 MFMA, self-converting B, 64x64 tiles) ----------------
__global__ __launch_bounds__(256) void k5_out(
    const short* __restrict__ gob, const float* __restrict__ Wo,
    float* __restrict__ out)
{
  __shared__ __align__(16) short As[64 * 40];
  __shared__ __align__(16) short Bs[64 * 40];
  const int tid = threadIdx.x;
  const int w = tid >> 6, l = tid & 63;
  const int r16 = l & 15, cg = l >> 4;
  const int bm = blockIdx.x & 15;
  const int bn = blockIdx.x >> 4;
  const int m0 = bm * 64, n0 = bn * 64;
  const int wr = w >> 1, wc = w & 1;
  const int strow = tid >> 2;
  const int scol = (tid & 3) * 8;
  const int kr = tid & 31;          // B staging: k row
  const int nb = (tid >> 5) * 8;    // B staging: n base

  v4f acc[2][2];
  #pragma unroll
  for (int i = 0; i < 2; ++i)
    #pragma unroll
    for (int j = 0; j < 2; ++j)
      acc[i][j] = (v4f){0.f, 0.f, 0.f, 0.f};

  for (int k0 = 0; k0 < CA; k0 += 32) {
    v8s av = *(const v8s*)(gob + (size_t)(m0 + strow) * CA + k0 + scol);
    v4f w0 = *(const v4f*)(Wo + (size_t)(k0 + kr) * HC + n0 + nb);
    v4f w1 = *(const v4f*)(Wo + (size_t)(k0 + kr) * HC + n0 + nb + 4);
    __syncthreads();
    *(v8s*)(As + (size_t)strow * 40 + scol) = av;
    #pragma unroll
    for (int i = 0; i < 4; ++i) Bs[(nb + i) * 40 + kr] = f2bf(w0[i]);
    #pragma unroll
    for (int i = 0; i < 4; ++i) Bs[(nb + 4 + i) * 40 + kr] = f2bf(w1[i]);
    __syncthreads();
    v8s af[2], bf[2];
    #pragma unroll
    for (int m = 0; m < 2; ++m)
      af[m] = *(const v8s*)(As + (wr * 32 + m * 16 + r16) * 40 + cg * 8);
    #pragma unroll
    for (int n = 0; n < 2; ++n)
      bf[n] = *(const v8s*)(Bs + (wc * 32 + n * 16 + r16) * 40 + cg * 8);
    #pragma unroll
    for (int m = 0; m < 2; ++m)
      #pragma unroll
      for (int n = 0; n < 2; ++n)
        acc[m][n] = __builtin_amdgcn_mfma_f32_16x16x32_bf16(af[m], bf[n], acc[m][n], 0, 0, 0);
  }

  #pragma unroll
  for (int n = 0; n < 2; ++n) {
    const int nc = n0 + wc * 32 + n * 16 + r16;
    const int rbase = m0 + wr * 32 + cg * 4;
    #pragma unroll
    for (int m = 0; m < 2; ++m)
      #pragma unroll
      for (int j = 0; j < 4; ++j)
        out[(size_t)(rbase + m * 16 + j) * CA + nc] = acc[m][n][j];
  }
}

extern "C" void kernel_launch(void* const* d_in, const int* in_sizes, int n_in,
                              void* d_out, int out_size, void* d_ws, size_t ws_size,
                              hipStream_t stream) {
  const float* a      = (const float*)d_in[0];
  const float* z      = (const float*)d_in[1];
  const float* mask   = (const float*)d_in[2];
  const float* ln_a_w = (const float*)d_in[3];
  const float* ln_a_b = (const float*)d_in[4];
  const float* ln_z_w = (const float*)d_in[5];
  const float* ln_z_b = (const float*)d_in[6];
  const float* Wq     = (const float*)d_in[7];
  const float* bq     = (const float*)d_in[8];
  const float* Wk     = (const float*)d_in[9];
  const float* Wv     = (const float*)d_in[10];
  const float* Wb     = (const float*)d_in[11];
  const float* Wg     = (const float*)d_in[12];
  const float* Wo     = (const float*)d_in[13];
  float* out = (float*)d_out;

  char* ws = (char*)d_ws;
  short* qb    = (short*)(ws);                               // 1.5 MB
  short* kb    = (short*)(ws + (2ull << 20));                // 1.5 MB
  short* vT    = (short*)(ws + (4ull << 20));                // 1.5 MB
  float* gbuf  = (float*)(ws + (6ull << 20));                // 3 MB
  short* gob   = (short*)(ws + (10ull << 20));               // 1.5 MB
  short* bpair = (short*)(ws + (12ull << 20));               // 32 MB

  k23_mega<<<192 + 4096, 256, 0, stream>>>(a, ln_a_w, ln_a_b, Wq, Wk, Wv, Wg,
                                           bq, z, ln_z_w, ln_z_b, Wb,
                                           qb, kb, vT, gbuf, bpair);
  k45_attn<<<1024, 512, 0, stream>>>(qb, kb, vT, bpair, mask, gbuf, gob);
  k5_out<<<192, 256, 0, stream>>>(gob, Wo, out);
}

// Round 13
// 172.740 us; speedup vs baseline: 1.1003x; 1.1003x over previous
//
#include <hip/hip_runtime.h>

#define NSEQ 1024
#define CA   768
#define CZ   128
#define NH   16
#define CHD  48
#define HC   768
#define INV_SQRT_CH 0.14433756729740643f

typedef float v4f __attribute__((ext_vector_type(4)));
typedef short v8s __attribute__((ext_vector_type(8)));

__device__ __forceinline__ short f2bf(float f) {
  union { float f; unsigned u; } v; v.f = f;
  unsigned r = v.u + 0x7fffu + ((v.u >> 16) & 1u);
  return (short)(r >> 16);
}
__device__ __forceinline__ float bf2f(short s) {
  union { unsigned u; float f; } v;
  v.u = ((unsigned)(unsigned short)s) << 16;
  return v.f;
}
__device__ __forceinline__ unsigned cvtpk(float lo, float hi) {
  unsigned r;
  asm("v_cvt_pk_bf16_f32 %0, %1, %2" : "=v"(r) : "v"(lo), "v"(hi));
  return r;
}

// ---------------- K_FRONT: block 0 = prep, 1..720 = weight conv, 721..1744 = LN(a) ----------------
__global__ __launch_bounds__(256) void k_front(
    const float* __restrict__ lnzw, const float* __restrict__ lnzb,
    const float* __restrict__ Wb, short* __restrict__ wWp, float* __restrict__ S1bW,
    const float* __restrict__ Wq, const float* __restrict__ Wk,
    const float* __restrict__ Wv, const float* __restrict__ Wg,
    const float* __restrict__ Wo, short* __restrict__ WT, short* __restrict__ WoT,
    const float* __restrict__ a, const float* __restrict__ lnaw,
    const float* __restrict__ lnab, short* __restrict__ anb)
{
  __shared__ __align__(16) char fsm[64 * 65 * 4];
  const int bid = blockIdx.x;
  const int t = threadIdx.x;

  if (bid == 0) {
    const int s = t >> 6, l = t & 63;
    const int r16 = l & 15, cg = l >> 4;
    float v[8];
    #pragma unroll
    for (int j = 0; j < 8; ++j) {
      int d = s * 32 + cg * 8 + j;
      v[j] = lnzw[d] * Wb[d * NH + r16];
    }
    uint4 pk;
    pk.x = cvtpk(v[0], v[1]); pk.y = cvtpk(v[2], v[3]);
    pk.z = cvtpk(v[4], v[5]); pk.w = cvtpk(v[6], v[7]);
    *(uint4*)(wWp + (s * 64 + l) * 8) = pk;
    if (t < NH) {
      float s1 = 0.f, bw = 0.f;
      for (int d = 0; d < CZ; ++d) {
        float wb = Wb[d * NH + t];
        s1 += bf2f(f2bf(lnzw[d] * wb));
        bw += lnzb[d] * wb;
      }
      S1bW[t] = s1;
      S1bW[NH + t] = bw;
    }
  } else if (bid <= 720) {
    float (*tile)[65] = (float(*)[65])fsm;
    const int cb = bid - 1;
    const int mat = cb / 144, rem = cb % 144;
    const int tk = rem % 12, tn = rem / 12;
    const int k0 = tk * 64, n0 = tn * 64;
    const float* __restrict__ W =
        (mat == 0) ? Wq : (mat == 1) ? Wk : (mat == 2) ? Wv : (mat == 3) ? Wg : Wo;
    const float s = (mat == 0) ? INV_SQRT_CH : 1.f;
    const int rr = t >> 4, cc = (t & 15) * 4;
    #pragma unroll
    for (int r = 0; r < 4; ++r) {
      v4f v = *(const v4f*)(W + (size_t)(k0 + r * 16 + rr) * HC + n0 + cc);
      tile[r * 16 + rr][cc + 0] = v[0];
      tile[r * 16 + rr][cc + 1] = v[1];
      tile[r * 16 + rr][cc + 2] = v[2];
      tile[r * 16 + rr][cc + 3] = v[3];
    }
    __syncthreads();
    short* dst = (mat < 4) ? (WT + (size_t)mat * HC * CA) : WoT;
    #pragma unroll
    for (int r = 0; r < 4; ++r) {
      const int nr = r * 16 + rr;
      uint2 pk;
      pk.x = cvtpk(tile[cc + 0][nr] * s, tile[cc + 1][nr] * s);
      pk.y = cvtpk(tile[cc + 2][nr] * s, tile[cc + 3][nr] * s);
      *(uint2*)(dst + (size_t)(n0 + nr) * CA + k0 + cc) = pk;
    }
  } else {
    float* red = (float*)fsm;
    const int row = bid - 721;
    const float* ar = a + (size_t)row * CA;
    float x[3];
    float s = 0.f, s2 = 0.f;
    #pragma unroll
    for (int i = 0; i < 3; ++i) {
      x[i] = ar[t + i * 256];
      s += x[i]; s2 += x[i] * x[i];
    }
    #pragma unroll
    for (int off = 1; off < 64; off <<= 1) {
      s += __shfl_xor(s, off);
      s2 += __shfl_xor(s2, off);
    }
    const int wv = t >> 6;
    if ((t & 63) == 0) { red[wv] = s; red[4 + wv] = s2; }
    __syncthreads();
    s = red[0] + red[1] + red[2] + red[3];
    s2 = red[4] + red[5] + red[6] + red[7];
    const float m = s * (1.f / CA);
    const float var = s2 * (1.f / CA) - m * m;
    const float rs = rsqrtf(var + 1e-5f);
    #pragma unroll
    for (int i = 0; i < 3; ++i) {
      int c = t + i * 256;
      anb[(size_t)row * CA + c] = f2bf((x[i] - m) * rs * lnaw[c] + lnab[c]);
    }
  }
}

// ---------------- K23: mega {blocks 0..191 = QKVG GEMM} + {192..4287 = z-bias} ----------------
__global__ __launch_bounds__(256) void k23_mega(
    const short* __restrict__ anb, const short* __restrict__ WT,
    const float* __restrict__ bq, const float* __restrict__ z,
    const short* __restrict__ wWp, const float* __restrict__ S1bW,
    short* __restrict__ qb, short* __restrict__ kb, short* __restrict__ vT,
    float* __restrict__ gbuf, short* __restrict__ bpair)
{
  __shared__ __align__(16) char smem[20480];
  const int tid = threadIdx.x;
  const int w = tid >> 6, l = tid & 63;
  const int r16 = l & 15, cg = l >> 4;

  if (blockIdx.x < 192) {
    // ---------- QKVG bf16 MFMA GEMM ----------
    short* As = (short*)smem;            // [128][40]
    short* Bs = (short*)(smem + 10240);  // [128][40]
    const int bm = blockIdx.x & 7;
    const int bnb = blockIdx.x >> 3;     // 0..23
    const int m0 = bm * 128, n0 = bnb * 128;
    const int wr = w >> 1, wc = w & 1;
    const int strow = w * 16 + (l >> 2);
    const int scol = (l & 3) * 8;

    v4f acc[4][4];
    #pragma unroll
    for (int i = 0; i < 4; ++i)
      #pragma unroll
      for (int j = 0; j < 4; ++j)
        acc[i][j] = (v4f){0.f, 0.f, 0.f, 0.f};

    for (int k0 = 0; k0 < CA; k0 += 32) {
      v8s av0 = *(const v8s*)(anb + (size_t)(m0 + strow) * CA + k0 + scol);
      v8s av1 = *(const v8s*)(anb + (size_t)(m0 + 64 + strow) * CA + k0 + scol);
      v8s bv0 = *(const v8s*)(WT + (size_t)(n0 + strow) * CA + k0 + scol);
      v8s bv1 = *(const v8s*)(WT + (size_t)(n0 + 64 + strow) * CA + k0 + scol);
      __syncthreads();
      *(v8s*)(As + (size_t)strow * 40 + scol) = av0;
      *(v8s*)(As + (size_t)(64 + strow) * 40 + scol) = av1;
      *(v8s*)(Bs + (size_t)strow * 40 + scol) = bv0;
      *(v8s*)(Bs + (size_t)(64 + strow) * 40 + scol) = bv1;
      __syncthreads();
      v8s a[4], b[4];
      #pragma unroll
      for (int m = 0; m < 4; ++m)
        a[m] = *(const v8s*)(As + (wr * 64 + m * 16 + r16) * 40 + cg * 8);
      #pragma unroll
      for (int n = 0; n < 4; ++n)
        b[n] = *(const v8s*)(Bs + (wc * 64 + n * 16 + r16) * 40 + cg * 8);
      #pragma unroll
      for (int m = 0; m < 4; ++m)
        #pragma unroll
        for (int n = 0; n < 4; ++n)
          acc[m][n] = __builtin_amdgcn_mfma_f32_16x16x32_bf16(a[m], b[n], acc[m][n], 0, 0, 0);
    }

    const int matsel = n0 / HC;
    #pragma unroll
    for (int n = 0; n < 4; ++n) {
      const int nc = (n0 % HC) + wc * 64 + n * 16 + r16;
      const int rbase = m0 + wr * 64 + cg * 4;
      if (matsel == 0) {
        const float bqs = bq[nc] * INV_SQRT_CH;
        #pragma unroll
        for (int m = 0; m < 4; ++m)
          #pragma unroll
          for (int j = 0; j < 4; ++j)
            qb[(size_t)(rbase + m * 16 + j) * HC + nc] = f2bf(acc[m][n][j] + bqs);
      } else if (matsel == 1) {
        #pragma unroll
        for (int m = 0; m < 4; ++m)
          #pragma unroll
          for (int j = 0; j < 4; ++j)
            kb[(size_t)(rbase + m * 16 + j) * HC + nc] = f2bf(acc[m][n][j]);
      } else if (matsel == 2) {
        #pragma unroll
        for (int m = 0; m < 4; ++m) {
          uint2 pk;
          pk.x = cvtpk(acc[m][n][0], acc[m][n][1]);
          pk.y = cvtpk(acc[m][n][2], acc[m][n][3]);
          *(uint2*)(vT + (size_t)nc * NSEQ + rbase + m * 16) = pk;
        }
      } else {
        #pragma unroll
        for (int m = 0; m < 4; ++m)
          #pragma unroll
          for (int j = 0; j < 4; ++j)
            gbuf[(size_t)(rbase + m * 16 + j) * HC + nc] =
                1.f / (1.f + __expf(-acc[m][n][j]));
      }
    }
  } else {
    // ---------- z-bias, barrier-free, software-pipelined, wave-private ----------
    const int zbid = blockIdx.x - 192;   // 0..4095
    short* bl = (short*)smem + w * (16 * 68);
    const int q = zbid >> 2;
    const int kw = ((zbid & 3) << 8) + w * 64;

    v8s bfrag[4];
    #pragma unroll
    for (int s = 0; s < 4; ++s) bfrag[s] = *(const v8s*)(wWp + (s * 64 + l) * 8);
    const float S1 = S1bW[r16];
    const float bW = S1bW[NH + r16];

    const float* __restrict__ zbase = z + ((size_t)q * NSEQ + kw + r16) * CZ;

    v4f zb[8];
    #pragma unroll
    for (int s = 0; s < 4; ++s) {
      zb[2 * s]     = *(const v4f*)(zbase + s * 32 + cg * 8);
      zb[2 * s + 1] = *(const v4f*)(zbase + s * 32 + cg * 8 + 4);
    }

    for (int kt = 0; kt < 4; ++kt) {
      v4f zn[8];
      if (kt < 3) {
        const float* __restrict__ zr2 = zbase + (size_t)(kt + 1) * 16 * CZ;
        #pragma unroll
        for (int s = 0; s < 4; ++s) {
          zn[2 * s]     = *(const v4f*)(zr2 + s * 32 + cg * 8);
          zn[2 * s + 1] = *(const v4f*)(zr2 + s * 32 + cg * 8 + 4);
        }
      }

      float sum = 0.f, sum2 = 0.f;
      v8s afrag[4];
      #pragma unroll
      for (int s = 0; s < 4; ++s) {
        v4f z0 = zb[2 * s], z1 = zb[2 * s + 1];
        #pragma unroll
        for (int j = 0; j < 4; ++j) {
          sum += z0[j] + z1[j];
          sum2 += z0[j] * z0[j] + z1[j] * z1[j];
        }
        union { v8s s8; unsigned u[4]; } fu;
        fu.u[0] = cvtpk(z0[0], z0[1]);
        fu.u[1] = cvtpk(z0[2], z0[3]);
        fu.u[2] = cvtpk(z1[0], z1[1]);
        fu.u[3] = cvtpk(z1[2], z1[3]);
        afrag[s] = fu.s8;
      }
      sum  += __shfl_xor(sum, 16);  sum  += __shfl_xor(sum, 32);
      sum2 += __shfl_xor(sum2, 16); sum2 += __shfl_xor(sum2, 32);
      const float mean = sum * (1.f / CZ);
      const float var = sum2 * (1.f / CZ) - mean * mean;
      const float rs = rsqrtf(var + 1e-5f);

      v4f acc = {0.f, 0.f, 0.f, 0.f};
      #pragma unroll
      for (int s = 0; s < 4; ++s)
        acc = __builtin_amdgcn_mfma_f32_16x16x32_bf16(afrag[s], bfrag[s], acc, 0, 0, 0);

      float bv[4];
      #pragma unroll
      for (int j = 0; j < 4; ++j) {
        int src = cg * 4 + j;
        float mj = __shfl(mean, src);
        float rj = __shfl(rs, src);
        bv[j] = rj * (acc[j] - mj * S1) + bW;
      }
      *(unsigned*)&bl[r16 * 68 + kt * 16 + cg * 4]     = cvtpk(bv[0], bv[1]);
      *(unsigned*)&bl[r16 * 68 + kt * 16 + cg * 4 + 2] = cvtpk(bv[2], bv[3]);

      if (kt < 3) {
        #pragma unroll
        for (int i = 0; i < 8; ++i) zb[i] = zn[i];
      }
    }

    asm volatile("s_waitcnt lgkmcnt(0)" ::: "memory");
    __builtin_amdgcn_sched_barrier(0);

    const int h = l >> 2, ck = (l & 3) * 16;
    v8s o0 = *(const v8s*)(bl + h * 68 + ck);
    v8s o1 = *(const v8s*)(bl + h * 68 + ck + 8);
    short* dst = bpair + (size_t)h * NSEQ * NSEQ + (size_t)q * NSEQ + kw + ck;
    *(v8s*)(dst)     = o0;
    *(v8s*)(dst + 8) = o1;
  }
}

// ---------------- K45: flash attention + in-block combine + gate ----------------
#define PL_STRIDE 136
#define PO_STRIDE 52
__global__ __launch_bounds__(512) void k45_attn(
    const short* __restrict__ qb, const short* __restrict__ kb,
    const short* __restrict__ vT, const short* __restrict__ bpair,
    const float* __restrict__ mask, const float* __restrict__ gbuf,
    short* __restrict__ gob)
{
  const int h = blockIdx.x & 15;
  const int qt = blockIdx.x >> 4;
  const int tid = threadIdx.x;
  const int w = tid >> 6, l = tid & 63;
  const int r16 = l & 15, cg = l >> 4;
  const int q0 = qt * 16;
  const int k0 = w * 128;

  __shared__ __align__(16) short plds[8][16 * PL_STRIDE];
  __shared__ __align__(16) float po_lds[8][16][PO_STRIDE];
  __shared__ __align__(16) float ml_lds[8][16][2];
  short* pl = &plds[w][0];

  const v8s vzero = {0, 0, 0, 0, 0, 0, 0, 0};
  v8s qf0, qf1;
  {
    const short* qp = qb + (size_t)(q0 + r16) * HC + h * CHD;
    qf0 = *(const v8s*)(qp + cg * 8);
    qf1 = (cg < 2) ? *(const v8s*)(qp + 32 + cg * 8) : vzero;
  }

  const size_t bpb = (size_t)h * NSEQ * NSEQ;
  {
    const int srow = l >> 2;
    const int scol = (l & 3) * 32;
    const short* bsrc = bpair + bpb + (size_t)(q0 + srow) * NSEQ + k0 + scol;
    short* bdst = pl + srow * PL_STRIDE + scol;
    v8s t0 = *(const v8s*)(bsrc);
    v8s t1 = *(const v8s*)(bsrc + 8);
    v8s t2 = *(const v8s*)(bsrc + 16);
    v8s t3 = *(const v8s*)(bsrc + 24);
    *(v8s*)(bdst)      = t0;
    *(v8s*)(bdst + 8)  = t1;
    *(v8s*)(bdst + 16) = t2;
    *(v8s*)(bdst + 24) = t3;
  }

  v4f cs[8];
  #pragma unroll
  for (int kt = 0; kt < 8; ++kt) {
    const short* kp = kb + (size_t)(k0 + kt * 16 + r16) * HC + h * CHD;
    v8s b0 = *(const v8s*)(kp + cg * 8);
    v8s b1 = (cg < 2) ? *(const v8s*)(kp + 32 + cg * 8) : vzero;
    v4f tacc = {0.f, 0.f, 0.f, 0.f};
    tacc = __builtin_amdgcn_mfma_f32_16x16x32_bf16(qf0, b0, tacc, 0, 0, 0);
    tacc = __builtin_amdgcn_mfma_f32_16x16x32_bf16(qf1, b1, tacc, 0, 0, 0);
    cs[kt] = tacc;
  }

  #pragma unroll
  for (int kt = 0; kt < 8; ++kt) {
    const int kc = k0 + kt * 16 + r16;
    const float mb = (mask[kc] - 1.f) * 1e9f;
    #pragma unroll
    for (int j = 0; j < 4; ++j)
      cs[kt][j] += bf2f(pl[(cg * 4 + j) * PL_STRIDE + kt * 16 + r16]) + mb;
  }

  float mx4[4], ls4[4];
  #pragma unroll
  for (int j = 0; j < 4; ++j) {
    float mx = fmaxf(fmaxf(fmaxf(cs[0][j], cs[1][j]), fmaxf(cs[2][j], cs[3][j])),
                     fmaxf(fmaxf(cs[4][j], cs[5][j]), fmaxf(cs[6][j], cs[7][j])));
    mx = fmaxf(mx, __shfl_xor(mx, 1));
    mx = fmaxf(mx, __shfl_xor(mx, 2));
    mx = fmaxf(mx, __shfl_xor(mx, 4));
    mx = fmaxf(mx, __shfl_xor(mx, 8));
    mx4[j] = mx;
    float p[8];
    #pragma unroll
    for (int kt = 0; kt < 8; ++kt) p[kt] = __expf(cs[kt][j] - mx);
    float rsum = ((p[0] + p[1]) + (p[2] + p[3])) + ((p[4] + p[5]) + (p[6] + p[7]));
    rsum += __shfl_xor(rsum, 1);
    rsum += __shfl_xor(rsum, 2);
    rsum += __shfl_xor(rsum, 4);
    rsum += __shfl_xor(rsum, 8);
    ls4[j] = rsum;
    const int rowb = (cg * 4 + j) * PL_STRIDE;
    #pragma unroll
    for (int t2 = 0; t2 < 4; ++t2) {
      unsigned u = cvtpk(p[2 * t2], p[2 * t2 + 1]);
      pl[rowb + (2 * t2) * 16 + r16] = (short)u;
      pl[rowb + (2 * t2 + 1) * 16 + r16] = (short)(u >> 16);
    }
  }
  asm volatile("s_waitcnt lgkmcnt(0)" ::: "memory");
  __builtin_amdgcn_sched_barrier(0);

  v4f of0 = {0, 0, 0, 0}, of1 = {0, 0, 0, 0}, of2 = {0, 0, 0, 0};
  #pragma unroll
  for (int ks4 = 0; ks4 < 4; ++ks4) {
    v8s pa = *(const v8s*)(pl + r16 * PL_STRIDE + ks4 * 32 + cg * 8);
    const short* vp = vT + (size_t)(h * CHD + r16) * NSEQ + k0 + ks4 * 32 + cg * 8;
    v8s bv0 = *(const v8s*)vp;
    v8s bv1 = *(const v8s*)(vp + 16 * NSEQ);
    v8s bv2 = *(const v8s*)(vp + 32 * NSEQ);
    of0 = __builtin_amdgcn_mfma_f32_16x16x32_bf16(pa, bv0, of0, 0, 0, 0);
    of1 = __builtin_amdgcn_mfma_f32_16x16x32_bf16(pa, bv1, of1, 0, 0, 0);
    of2 = __builtin_amdgcn_mfma_f32_16x16x32_bf16(pa, bv2, of2, 0, 0, 0);
  }

  #pragma unroll
  for (int j = 0; j < 4; ++j) {
    const int row = cg * 4 + j;
    po_lds[w][row][r16]      = of0[j];
    po_lds[w][row][16 + r16] = of1[j];
    po_lds[w][row][32 + r16] = of2[j];
    if (r16 == 0) {
      ml_lds[w][row][0] = mx4[j];
      ml_lds[w][row][1] = ls4[j];
    }
  }
  __syncthreads();

  {
    const int g = tid >> 5;
    const int lane = tid & 31;
    float mi[8], li[8];
    #pragma unroll
    for (int i = 0; i < 8; ++i) {
      mi[i] = ml_lds[i][g][0];
      li[i] = ml_lds[i][g][1];
    }
    float mstar = -1e30f;
    #pragma unroll
    for (int i = 0; i < 8; ++i) mstar = fmaxf(mstar, mi[i]);
    float wgt[8], L = 0.f;
    #pragma unroll
    for (int i = 0; i < 8; ++i) { wgt[i] = __expf(mi[i] - mstar); L += li[i] * wgt[i]; }
    const float inv = 1.f / L;
    const int q = q0 + g;
    {
      float o = 0.f;
      #pragma unroll
      for (int i = 0; i < 8; ++i) o += po_lds[i][g][lane] * wgt[i];
      const float gv = gbuf[(size_t)q * HC + h * CHD + lane];
      gob[(size_t)q * HC + h * CHD + lane] = f2bf(o * inv * gv);
    }
    if (lane < 16) {
      const int d = 32 + lane;
      float o = 0.f;
      #pragma unroll
      for (int i = 0; i < 8; ++i) o += po_lds[i][g][d] * wgt[i];
      const float gv = gbuf[(size_t)q * HC + h * CHD + d];
      gob[(size_t)q * HC + h * CHD + d] = f2bf(o * inv * gv);
    }
  }
}

// ---------------- K5: out = gob @ WoT^T (bf16 MFMA, 64x64 tiles, 192 blocks) ----------------
__global__ __launch_bounds__(256) void k5_out(
    const short* __restrict__ gob, const short* __restrict__ WoT,
    float* __restrict__ out)
{
  __shared__ __align__(16) short As[64 * 40];
  __shared__ __align__(16) short Bs[64 * 40];
  const int tid = threadIdx.x;
  const int w = tid >> 6, l = tid & 63;
  const int r16 = l & 15, cg = l >> 4;
  const int bm = blockIdx.x & 15;
  const int bn = blockIdx.x >> 4;
  const int m0 = bm * 64, n0 = bn * 64;
  const int wr = w >> 1, wc = w & 1;
  const int strow = tid >> 2;
  const int scol = (tid & 3) * 8;

  v4f acc[2][2];
  #pragma unroll
  for (int i = 0; i < 2; ++i)
    #pragma unroll
    for (int j = 0; j < 2; ++j)
      acc[i][j] = (v4f){0.f, 0.f, 0.f, 0.f};

  for (int k0 = 0; k0 < CA; k0 += 32) {
    v8s av = *(const v8s*)(gob + (size_t)(m0 + strow) * CA + k0 + scol);
    v8s bv = *(const v8s*)(WoT + (size_t)(n0 + strow) * CA + k0 + scol);
    __syncthreads();
    *(v8s*)(As + (size_t)strow * 40 + scol) = av;
    *(v8s*)(Bs + (size_t)strow * 40 + scol) = bv;
    __syncthreads();
    v8s a[2], b[2];
    #pragma unroll
    for (int m = 0; m < 2; ++m)
      a[m] = *(const v8s*)(As + (wr * 32 + m * 16 + r16) * 40 + cg * 8);
    #pragma unroll
    for (int n = 0; n < 2; ++n)
      b[n] = *(const v8s*)(Bs + (wc * 32 + n * 16 + r16) * 40 + cg * 8);
    #pragma unroll
    for (int m = 0; m < 2; ++m)
      #pragma unroll
      for (int n = 0; n < 2; ++n)
        acc[m][n] = __builtin_amdgcn_mfma_f32_16x16x32_bf16(a[m], b[n], acc[m][n], 0, 0, 0);
  }

  #pragma unroll
  for (int n = 0; n < 2; ++n) {
    const int nc = n0 + wc * 32 + n * 16 + r16;
    const int rbase = m0 + wr * 32 + cg * 4;
    #pragma unroll
    for (int m = 0; m < 2; ++m)
      #pragma unroll
      for (int j = 0; j < 4; ++j)
        out[(size_t)(rbase + m * 16 + j) * CA + nc] = acc[m][n][j];
  }
}

extern "C" void kernel_launch(void* const* d_in, const int* in_sizes, int n_in,
                              void* d_out, int out_size, void* d_ws, size_t ws_size,
                              hipStream_t stream) {
  const float* a      = (const float*)d_in[0];
  const float* z      = (const float*)d_in[1];
  const float* mask   = (const float*)d_in[2];
  const float* ln_a_w = (const float*)d_in[3];
  const float* ln_a_b = (const float*)d_in[4];
  const float* ln_z_w = (const float*)d_in[5];
  const float* ln_z_b = (const float*)d_in[6];
  const float* Wq     = (const float*)d_in[7];
  const float* bq     = (const float*)d_in[8];
  const float* Wk     = (const float*)d_in[9];
  const float* Wv     = (const float*)d_in[10];
  const float* Wb     = (const float*)d_in[11];
  const float* Wg     = (const float*)d_in[12];
  const float* Wo     = (const float*)d_in[13];
  float* out = (float*)d_out;

  char* ws = (char*)d_ws;
  short* anb   = (short*)(ws);                               // 1.5 MB
  short* WT    = (short*)(ws + (2ull << 20));                // 4.5 MB
  short* WoT   = (short*)(ws + (7ull << 20));                // 1.125 MB
  short* qb    = (short*)(ws + (9ull << 20));                // 1.5 MB
  short* kb    = (short*)(ws + (11ull << 20));               // 1.5 MB
  short* vT    = (short*)(ws + (13ull << 20));               // 1.5 MB
  float* gbuf  = (float*)(ws + (15ull << 20));               // 3 MB
  short* wWp   = (short*)(ws + (19ull << 20));               // 4 KB
  float* S1bW  = (float*)(ws + (19ull << 20) + 4096ull);     // 128 B
  short* gob   = (short*)(ws + (20ull << 20));               // 1.5 MB
  short* bpair = (short*)(ws + (22ull << 20));               // 32 MB

  k_front<<<1745, 256, 0, stream>>>(ln_z_w, ln_z_b, Wb, wWp, S1bW,
                                    Wq, Wk, Wv, Wg, Wo, WT, WoT,
                                    a, ln_a_w, ln_a_b, anb);
  k23_mega<<<192 + 4096, 256, 0, stream>>>(anb, WT, bq, z, wWp, S1bW,
                                           qb, kb, vT, gbuf, bpair);
  k45_attn<<<1024, 512, 0, stream>>>(qb, kb, vT, bpair, mask, gbuf, gob);
  k5_out<<<192, 256, 0, stream>>>(gob, WoT, out);
}